// Round 3
// baseline (521.046 us; speedup 1.0000x reference)
//
#include <hip/hip_runtime.h>
#include <hip/hip_bf16.h>

// EncoderBlock: LN1 -> MHA -> +res -> LN2 -> MLP(GELU exact) -> +res
// B=16 S=512 E=1024 F=4096 H=16 D=64, fp32 in/out, bf16 MFMA internally.
//
// R3: constexpr N/K + SGPR-uniform staging addresses + hoisted LDS offsets
//     (kill ~400 VALU/iter rematerialization; VALUBusy 56 -> ~35 predicted),
//     launch_bounds(256,3), fused single prep_weights launch.
//
// ws layout (bytes):
//   0        wqkvT  [3072][1024] bf16   6 MB   (wq^T|wk^T|wv^T)
//   6 MB     woT    [1024][1024] bf16   2 MB
//   8 MB     w1T    [4096][1024] bf16   8 MB
//   16 MB    w2T    [1024][4096] bf16   8 MB
//   24 MB    qk     [8192][2048] bf16  32 MB   (Q|K)   -> later x fp32 [8192][1024] 32 MB
//   56 MB    Vt     [256][64][512] bf16 16 MB          -> later y_ln bf16 16 MB
//   72 MB    abuf   [8192][1024] bf16  16 MB (ln1/attn)-> later h bf16 [8192][4096] 64 MB (72..136)
//   136 MB   bqkv   [3072] f32  12 KB

typedef __bf16 bf16x8 __attribute__((ext_vector_type(8)));
typedef __bf16 bf16x4 __attribute__((ext_vector_type(4)));
typedef float  f32x4  __attribute__((ext_vector_type(4)));

#define EPI_QKV  0
#define EPI_RES  1
#define EPI_GELU 2

__device__ __forceinline__ void async_copy16(const void* g, void* l) {
  __builtin_amdgcn_global_load_lds((const __attribute__((address_space(1))) void*)g,
                                   (__attribute__((address_space(3))) void*)l, 16, 0, 0);
}

// ---------------- fused weight prep: 6 transposes (fp32->bf16, [K][N]->[N][K]) + bias concat
__global__ __launch_bounds__(256) void prep_weights(
    const float* __restrict__ wq, const float* __restrict__ wk,
    const float* __restrict__ wv, const float* __restrict__ wo,
    const float* __restrict__ w1, const float* __restrict__ w2,
    const float* __restrict__ bq, const float* __restrict__ bk,
    const float* __restrict__ bv,
    __bf16* __restrict__ wqkvT, __bf16* __restrict__ woT,
    __bf16* __restrict__ w1T, __bf16* __restrict__ w2T, float* __restrict__ bqkv) {
  const int bid = blockIdx.x;
  if (bid >= 12288) { // 12 bias blocks -> 3072 elements
    const int i = (bid - 12288) * 256 + threadIdx.x;
    bqkv[i] = (i < 1024) ? bq[i] : ((i < 2048) ? bk[i - 1024] : bv[i - 2048]);
    return;
  }
  const float* in;
  __bf16* out;
  int K, N, tile;
  if (bid < 4096) { // four 1024x1024 weights, 1024 tiles (32x32) each
    const int w = bid >> 10;
    tile = bid & 1023;
    in = (w == 0) ? wq : (w == 1) ? wk : (w == 2) ? wv : wo;
    out = (w == 3) ? woT : (wqkvT + (size_t)w * 1024 * 1024);
    K = 1024; N = 1024;
  } else if (bid < 8192) { tile = bid - 4096; in = w1; out = w1T; K = 1024; N = 4096; }
  else                   { tile = bid - 8192; in = w2; out = w2T; K = 4096; N = 1024; }
  const int ntx = N >> 5;
  const int bx = tile % ntx, by = tile / ntx;
  const int n0 = bx * 32, k0 = by * 32;

  __shared__ float tilebuf[32][33];
  const int tx = threadIdx.x & 31, ty = threadIdx.x >> 5; // 32x8
#pragma unroll
  for (int i = 0; i < 4; i++)
    tilebuf[ty + i * 8][tx] = in[(size_t)(k0 + ty + i * 8) * N + n0 + tx];
  __syncthreads();
#pragma unroll
  for (int i = 0; i < 4; i++)
    out[(size_t)(n0 + ty + i * 8) * K + k0 + tx] = (__bf16)tilebuf[tx][ty + i * 8];
}

// ---------------- layernorm: one block per row (E=1024, 256 thr * float4)
__device__ __forceinline__ float block_sum(float v, float* red) {
#pragma unroll
  for (int off = 32; off; off >>= 1) v += __shfl_down(v, off);
  const int w = threadIdx.x >> 6;
  __syncthreads();
  if ((threadIdx.x & 63) == 0) red[w] = v;
  __syncthreads();
  return red[0] + red[1] + red[2] + red[3];
}

__global__ __launch_bounds__(256) void ln_kernel(const float* __restrict__ x,
                                                 const float* __restrict__ g,
                                                 const float* __restrict__ bta,
                                                 __bf16* __restrict__ out) {
  __shared__ float red[8];
  const int row = blockIdx.x, t = threadIdx.x;
  const float4 v = ((const float4*)(x + (size_t)row * 1024))[t];
  float s = v.x + v.y + v.z + v.w;
  s = block_sum(s, red);
  const float mean = s * (1.0f / 1024.0f);
  const float d0 = v.x - mean, d1 = v.y - mean, d2 = v.z - mean, d3 = v.w - mean;
  float vs = d0 * d0 + d1 * d1 + d2 * d2 + d3 * d3;
  vs = block_sum(vs, red);
  const float rstd = rsqrtf(vs * (1.0f / 1024.0f) + 1e-5f);
  const float4 gg = ((const float4*)g)[t];
  const float4 bb = ((const float4*)bta)[t];
  bf16x4 o;
  o[0] = (__bf16)(d0 * rstd * gg.x + bb.x);
  o[1] = (__bf16)(d1 * rstd * gg.y + bb.y);
  o[2] = (__bf16)(d2 * rstd * gg.z + bb.z);
  o[3] = (__bf16)(d3 * rstd * gg.w + bb.w);
  ((bf16x4*)out)[(size_t)row * 256 + t] = o;
}

// ---------------- GEMM: C[8192][N] = A[8192][K](bf16) * Bt[N][K](bf16) + bias
// 128x128 tile, BK=64, XOR-swizzled LDS (0 conflicts), 4 waves, 16x16x32 MFMA.
// N,K constexpr: uniform staging base goes to SGPRs, lane offsets loop-invariant.
template <int EPI, int N, int K>
__global__ __launch_bounds__(256, 3) void gemm_bt(const __bf16* __restrict__ A,
                                                  const __bf16* __restrict__ Bt,
                                                  const float* __restrict__ bias,
                                                  const float* __restrict__ res,
                                                  void* __restrict__ out,
                                                  void* __restrict__ out2) {
  __shared__ __bf16 lA[128 * 64];
  __shared__ __bf16 lB[128 * 64];
  const int t = threadIdx.x;
  const int wave = t >> 6, lane = t & 63;
  const int lm = lane & 15, lq = lane >> 4;

  // XCD-aware tile mapping (Mtiles = 64, divisible by 8)
  constexpr int Ntiles = N / 128;
  const int flat = blockIdx.y * Ntiles + blockIdx.x;
  const int xcd = flat & 7;
  const int local = flat >> 3;
  const int tn = local % Ntiles;
  const int tm = (local / Ntiles) * 8 + xcd;
  const int m0 = tm * 128, n0 = tn * 128;
  const int wm = (wave & 1) * 64, wn = (wave >> 1) * 64;

  f32x4 acc[4][4] = {};

  // staging: thread t covers rows {srow, srow+32, srow+64, srow+96}; 16B chunk
  // slot (t%8) holds global chunk (t%8)^(srow&7)  (XOR swizzle on the SOURCE,
  // LDS dest stays lane-contiguous as global_load_lds requires).
  const int srow = t >> 3;
  const int schunk = (t & 7) ^ (srow & 7);
  const unsigned aOff = (unsigned)(m0 + srow) * K + schunk * 8; // lane part, 32-bit
  const unsigned bOff = (unsigned)(n0 + srow) * K + schunk * 8;

  // LDS read offsets (elements), loop-invariant: row panel base + XOR'd slot
  const int swz = lm & 7;
  const int aBase = (wm + lm) * 64;
  const int bBase = (wn + lm) * 64;
  const int sl0 = ((lq ^ swz) * 8);
  const int sl1 = (((4 + lq) ^ swz) * 8);

  for (int k0 = 0; k0 < K; k0 += 64) {
#pragma unroll
    for (int i = 0; i < 4; i++) {
      // uniform (SGPR) base: A + k0 + i*32*K ; lane (VGPR) offset: aOff
      async_copy16((A + k0 + i * 32 * K) + aOff, lA + i * 2048 + t * 8);
      async_copy16((Bt + k0 + i * 32 * K) + bOff, lB + i * 2048 + t * 8);
    }
    __syncthreads();
#pragma unroll
    for (int kk = 0; kk < 2; kk++) {
      const int sl = kk ? sl1 : sl0;
      bf16x8 af[4], bf[4];
#pragma unroll
      for (int i = 0; i < 4; i++) {
        af[i] = *(const bf16x8*)&lA[aBase + i * 1024 + sl];
        bf[i] = *(const bf16x8*)&lB[bBase + i * 1024 + sl];
      }
#pragma unroll
      for (int mi = 0; mi < 4; mi++)
#pragma unroll
        for (int ni = 0; ni < 4; ni++)
          acc[mi][ni] = __builtin_amdgcn_mfma_f32_16x16x32_bf16(af[mi], bf[ni], acc[mi][ni], 0, 0, 0);
    }
    __syncthreads();
  }

  // epilogue. C/D layout: col = lane&15, row = (lane>>4)*4 + reg  [m89/m91]
#pragma unroll
  for (int mi = 0; mi < 4; mi++) {
    const int gr = m0 + wm + mi * 16 + lq * 4;
#pragma unroll
    for (int ni = 0; ni < 4; ni++) {
      const int gc = n0 + wn + ni * 16 + lm;
      const float bv = bias[gc];
#pragma unroll
      for (int r = 0; r < 4; r++) {
        float v = acc[mi][ni][r] + bv;
        const int row = gr + r;
        if (EPI == EPI_GELU) {
          v = 0.5f * v * (1.0f + erff(v * 0.70710678118654752f));
          ((__bf16*)out)[(size_t)row * N + gc] = (__bf16)v;
        } else if (EPI == EPI_RES) {
          ((float*)out)[(size_t)row * N + gc] = v + res[(size_t)row * N + gc];
        } else { // EPI_QKV: Q|K -> qk[8192][2048]; V -> Vt[b][h][d][s]
          if (gc < 2048) {
            ((__bf16*)out)[(size_t)row * 2048 + gc] = (__bf16)v;
          } else {
            const int d = gc & 63, hh = (gc - 2048) >> 6;
            const int bb = row >> 9, ss = row & 511;
            ((__bf16*)out2)[(((size_t)bb * 16 + hh) * 64 + d) * 512 + ss] = (__bf16)v;
          }
        }
      }
    }
  }
}

// ---------------- flash attention: block = (b, h, 64 q-rows), 4 waves x 16 q-rows
// flat grid 2048, swizzled so the 8 q-tiles of one (b,h) share an XCD (K/V L2 reuse)
__global__ __launch_bounds__(256, 3) void attn_kernel(const __bf16* __restrict__ qk,
                                                      const __bf16* __restrict__ Vt,
                                                      __bf16* __restrict__ outA) {
  __shared__ __bf16 lK[64 * 64];      // [key][d]
  __shared__ __bf16 lV[64 * 64];      // [d][key]  (pre-transposed source)
  __shared__ __bf16 lP[4][16 * 64];   // per-wave P relayout buffer
  const int t = threadIdx.x, wave = t >> 6, lane = t & 63;
  const int lm = lane & 15, lq = lane >> 4;
  const int flat = blockIdx.x;
  const int xcd = flat & 7, local = flat >> 3;
  const int qt = local & 7;
  const int bh = (local >> 3) * 8 + xcd;
  const int h = bh & 15, b = bh >> 4;
  const int q0 = qt * 64 + wave * 16;

  // Q A-operand frags: A[m=lane&15][k=quad*8+j], two 32-wide d chunks
  const size_t qrow = (size_t)(b * 512 + q0 + lm) * 2048 + h * 64;
  bf16x8 aq0 = *(const bf16x8*)&qk[qrow + lq * 8];
  bf16x8 aq1 = *(const bf16x8*)&qk[qrow + 32 + lq * 8];

  float mrow[4] = {-3e38f, -3e38f, -3e38f, -3e38f};
  float lrow[4] = {0.f, 0.f, 0.f, 0.f};
  f32x4 o[4] = {};

  const __bf16* kSrc = qk + (size_t)(b * 512 + (t >> 3)) * 2048 + 1024 + h * 64 + (t & 7) * 8;
  const __bf16* vSrc = Vt + ((size_t)bh * 64 + (t >> 3)) * 512 + (t & 7) * 8;

  for (int kt = 0; kt < 8; kt++) {
    async_copy16(kSrc + (size_t)(kt * 64) * 2048, lK + t * 8);
    async_copy16(kSrc + (size_t)(kt * 64 + 32) * 2048, lK + 2048 + t * 8);
    async_copy16(vSrc + kt * 64, lV + t * 8);
    async_copy16(vSrc + kt * 64 + (size_t)32 * 512, lV + 2048 + t * 8);
    __syncthreads();

    // S = Q Kt^T  (16 q x 64 keys per wave)
    f32x4 s[4];
#pragma unroll
    for (int ni = 0; ni < 4; ni++) {
      bf16x8 bk0 = *(const bf16x8*)&lK[(ni * 16 + lm) * 64 + lq * 8];
      bf16x8 bk1 = *(const bf16x8*)&lK[(ni * 16 + lm) * 64 + 32 + lq * 8];
      f32x4 z = {};
      z = __builtin_amdgcn_mfma_f32_16x16x32_bf16(aq0, bk0, z, 0, 0, 0);
      z = __builtin_amdgcn_mfma_f32_16x16x32_bf16(aq1, bk1, z, 0, 0, 0);
      s[ni] = z;
    }
#pragma unroll
    for (int ni = 0; ni < 4; ni++)
#pragma unroll
      for (int r = 0; r < 4; r++) s[ni][r] *= 0.125f; // 1/sqrt(64)

    // online softmax; 16 lanes (one quad-row group) share each row
    float mnew[4], alpha[4];
#pragma unroll
    for (int r = 0; r < 4; r++) {
      float mx = fmaxf(fmaxf(s[0][r], s[1][r]), fmaxf(s[2][r], s[3][r]));
#pragma unroll
      for (int off = 1; off < 16; off <<= 1) mx = fmaxf(mx, __shfl_xor(mx, off));
      mnew[r] = fmaxf(mrow[r], mx);
      alpha[r] = __expf(mrow[r] - mnew[r]);
      mrow[r] = mnew[r];
    }
    float rs[4] = {0.f, 0.f, 0.f, 0.f};
#pragma unroll
    for (int ni = 0; ni < 4; ni++)
#pragma unroll
      for (int r = 0; r < 4; r++) {
        const float p = __expf(s[ni][r] - mnew[r]);
        s[ni][r] = p;
        rs[r] += p;
      }
#pragma unroll
    for (int r = 0; r < 4; r++) {
#pragma unroll
      for (int off = 1; off < 16; off <<= 1) rs[r] += __shfl_xor(rs[r], off);
      lrow[r] = lrow[r] * alpha[r] + rs[r];
    }

    // P: C-layout -> A-operand layout via per-wave LDS round trip (m120)
#pragma unroll
    for (int ni = 0; ni < 4; ni++)
#pragma unroll
      for (int r = 0; r < 4; r++)
        lP[wave][(lq * 4 + r) * 64 + ni * 16 + lm] = (__bf16)s[ni][r];
    asm volatile("s_waitcnt lgkmcnt(0)" ::: "memory");
    bf16x8 ap0 = *(const bf16x8*)&lP[wave][lm * 64 + lq * 8];
    bf16x8 ap1 = *(const bf16x8*)&lP[wave][lm * 64 + 32 + lq * 8];

#pragma unroll
    for (int di = 0; di < 4; di++)
#pragma unroll
      for (int r = 0; r < 4; r++) o[di][r] *= alpha[r];

    // O += P Vtile ; B-operand n = d (from lV[d][key], contiguous along key)
#pragma unroll
    for (int di = 0; di < 4; di++) {
      bf16x8 bv0 = *(const bf16x8*)&lV[(di * 16 + lm) * 64 + lq * 8];
      bf16x8 bv1 = *(const bf16x8*)&lV[(di * 16 + lm) * 64 + 32 + lq * 8];
      o[di] = __builtin_amdgcn_mfma_f32_16x16x32_bf16(ap0, bv0, o[di], 0, 0, 0);
      o[di] = __builtin_amdgcn_mfma_f32_16x16x32_bf16(ap1, bv1, o[di], 0, 0, 0);
    }
    __syncthreads();
  }

#pragma unroll
  for (int di = 0; di < 4; di++)
#pragma unroll
    for (int r = 0; r < 4; r++) {
      const float v = o[di][r] / lrow[r];
      outA[(size_t)(b * 512 + q0 + lq * 4 + r) * 1024 + h * 64 + di * 16 + lm] = (__bf16)v;
    }
}

extern "C" void kernel_launch(void* const* d_in, const int* in_sizes, int n_in,
                              void* d_out, int out_size, void* d_ws, size_t ws_size,
                              hipStream_t stream) {
  const float* input = (const float*)d_in[0];
  const float* ln1_g = (const float*)d_in[1];
  const float* ln1_b = (const float*)d_in[2];
  const float* wq = (const float*)d_in[3];
  const float* bq = (const float*)d_in[4];
  const float* wk = (const float*)d_in[5];
  const float* bk = (const float*)d_in[6];
  const float* wv = (const float*)d_in[7];
  const float* bv = (const float*)d_in[8];
  const float* wo = (const float*)d_in[9];
  const float* bo = (const float*)d_in[10];
  const float* ln2_g = (const float*)d_in[11];
  const float* ln2_b = (const float*)d_in[12];
  const float* w1 = (const float*)d_in[13];
  const float* b1 = (const float*)d_in[14];
  const float* w2 = (const float*)d_in[15];
  const float* b2 = (const float*)d_in[16];

  char* ws = (char*)d_ws;
  __bf16* wqkvT = (__bf16*)(ws + 0);
  __bf16* woT   = (__bf16*)(ws + ((size_t)6 << 20));
  __bf16* w1T   = (__bf16*)(ws + ((size_t)8 << 20));
  __bf16* w2T   = (__bf16*)(ws + ((size_t)16 << 20));
  __bf16* qkbuf = (__bf16*)(ws + ((size_t)24 << 20));
  __bf16* vtbuf = (__bf16*)(ws + ((size_t)56 << 20));
  __bf16* abuf  = (__bf16*)(ws + ((size_t)72 << 20));
  float*  xbuf  = (float*) (ws + ((size_t)24 << 20));
  __bf16* ylnbuf= (__bf16*)(ws + ((size_t)56 << 20));
  __bf16* hbuf  = (__bf16*)(ws + ((size_t)72 << 20));
  float*  bqkv  = (float*) (ws + ((size_t)136 << 20));

  const dim3 blk(256);
  prep_weights<<<12300, blk, 0, stream>>>(wq, wk, wv, wo, w1, w2, bq, bk, bv,
                                          wqkvT, woT, w1T, w2T, bqkv);

  ln_kernel<<<8192, blk, 0, stream>>>(input, ln1_g, ln1_b, abuf);
  gemm_bt<EPI_QKV, 3072, 1024><<<dim3(24, 64), blk, 0, stream>>>(
      abuf, wqkvT, bqkv, nullptr, qkbuf, vtbuf);
  attn_kernel<<<2048, blk, 0, stream>>>(qkbuf, vtbuf, abuf);
  gemm_bt<EPI_RES, 1024, 1024><<<dim3(8, 64), blk, 0, stream>>>(
      abuf, woT, bo, input, xbuf, nullptr);
  ln_kernel<<<8192, blk, 0, stream>>>(xbuf, ln2_g, ln2_b, ylnbuf);
  gemm_bt<EPI_GELU, 4096, 1024><<<dim3(32, 64), blk, 0, stream>>>(
      ylnbuf, w1T, b1, nullptr, hbuf, nullptr);
  gemm_bt<EPI_RES, 1024, 4096><<<dim3(8, 64), blk, 0, stream>>>(
      hbuf, w2T, b2, xbuf, d_out, nullptr);
}

// Round 4
// 509.442 us; speedup vs baseline: 1.0228x; 1.0228x over previous
//
#include <hip/hip_runtime.h>
#include <hip/hip_bf16.h>

// EncoderBlock: LN1 -> MHA -> +res -> LN2 -> MLP(GELU exact) -> +res
// B=16 S=512 E=1024 F=4096 H=16 D=64, fp32 in/out, bf16 MFMA internally.
//
// R4: gemm inner loop -> mfma_f32_32x32x16_bf16 (2382 TF ceiling vs 2075,
//     ~17% fewer MFMA-pipe cycles, same LDS traffic); revert launch_bounds
//     to (256,2) (R3's (256,3) cost occupancy 36->29 and regressed).
//
// ws layout (bytes):
//   0        wqkvT  [3072][1024] bf16   6 MB   (wq^T|wk^T|wv^T)
//   6 MB     woT    [1024][1024] bf16   2 MB
//   8 MB     w1T    [4096][1024] bf16   8 MB
//   16 MB    w2T    [1024][4096] bf16   8 MB
//   24 MB    qk     [8192][2048] bf16  32 MB   (Q|K)   -> later x fp32 [8192][1024] 32 MB
//   56 MB    Vt     [256][64][512] bf16 16 MB          -> later y_ln bf16 16 MB
//   72 MB    abuf   [8192][1024] bf16  16 MB (ln1/attn)-> later h bf16 [8192][4096] 64 MB (72..136)
//   136 MB   bqkv   [3072] f32  12 KB

typedef __bf16 bf16x8 __attribute__((ext_vector_type(8)));
typedef __bf16 bf16x4 __attribute__((ext_vector_type(4)));
typedef float  f32x4  __attribute__((ext_vector_type(4)));
typedef float  f32x16 __attribute__((ext_vector_type(16)));

#define EPI_QKV  0
#define EPI_RES  1
#define EPI_GELU 2

__device__ __forceinline__ void async_copy16(const void* g, void* l) {
  __builtin_amdgcn_global_load_lds((const __attribute__((address_space(1))) void*)g,
                                   (__attribute__((address_space(3))) void*)l, 16, 0, 0);
}

// ---------------- fused weight prep: 6 transposes (fp32->bf16, [K][N]->[N][K]) + bias concat
__global__ __launch_bounds__(256) void prep_weights(
    const float* __restrict__ wq, const float* __restrict__ wk,
    const float* __restrict__ wv, const float* __restrict__ wo,
    const float* __restrict__ w1, const float* __restrict__ w2,
    const float* __restrict__ bq, const float* __restrict__ bk,
    const float* __restrict__ bv,
    __bf16* __restrict__ wqkvT, __bf16* __restrict__ woT,
    __bf16* __restrict__ w1T, __bf16* __restrict__ w2T, float* __restrict__ bqkv) {
  const int bid = blockIdx.x;
  if (bid >= 12288) { // 12 bias blocks -> 3072 elements
    const int i = (bid - 12288) * 256 + threadIdx.x;
    bqkv[i] = (i < 1024) ? bq[i] : ((i < 2048) ? bk[i - 1024] : bv[i - 2048]);
    return;
  }
  const float* in;
  __bf16* out;
  int K, N, tile;
  if (bid < 4096) { // four 1024x1024 weights, 1024 tiles (32x32) each
    const int w = bid >> 10;
    tile = bid & 1023;
    in = (w == 0) ? wq : (w == 1) ? wk : (w == 2) ? wv : wo;
    out = (w == 3) ? woT : (wqkvT + (size_t)w * 1024 * 1024);
    K = 1024; N = 1024;
  } else if (bid < 8192) { tile = bid - 4096; in = w1; out = w1T; K = 1024; N = 4096; }
  else                   { tile = bid - 8192; in = w2; out = w2T; K = 4096; N = 1024; }
  const int ntx = N >> 5;
  const int bx = tile % ntx, by = tile / ntx;
  const int n0 = bx * 32, k0 = by * 32;

  __shared__ float tilebuf[32][33];
  const int tx = threadIdx.x & 31, ty = threadIdx.x >> 5; // 32x8
#pragma unroll
  for (int i = 0; i < 4; i++)
    tilebuf[ty + i * 8][tx] = in[(size_t)(k0 + ty + i * 8) * N + n0 + tx];
  __syncthreads();
#pragma unroll
  for (int i = 0; i < 4; i++)
    out[(size_t)(n0 + ty + i * 8) * K + k0 + tx] = (__bf16)tilebuf[tx][ty + i * 8];
}

// ---------------- layernorm: one block per row (E=1024, 256 thr * float4)
__device__ __forceinline__ float block_sum(float v, float* red) {
#pragma unroll
  for (int off = 32; off; off >>= 1) v += __shfl_down(v, off);
  const int w = threadIdx.x >> 6;
  __syncthreads();
  if ((threadIdx.x & 63) == 0) red[w] = v;
  __syncthreads();
  return red[0] + red[1] + red[2] + red[3];
}

__global__ __launch_bounds__(256) void ln_kernel(const float* __restrict__ x,
                                                 const float* __restrict__ g,
                                                 const float* __restrict__ bta,
                                                 __bf16* __restrict__ out) {
  __shared__ float red[8];
  const int row = blockIdx.x, t = threadIdx.x;
  const float4 v = ((const float4*)(x + (size_t)row * 1024))[t];
  float s = v.x + v.y + v.z + v.w;
  s = block_sum(s, red);
  const float mean = s * (1.0f / 1024.0f);
  const float d0 = v.x - mean, d1 = v.y - mean, d2 = v.z - mean, d3 = v.w - mean;
  float vs = d0 * d0 + d1 * d1 + d2 * d2 + d3 * d3;
  vs = block_sum(vs, red);
  const float rstd = rsqrtf(vs * (1.0f / 1024.0f) + 1e-5f);
  const float4 gg = ((const float4*)g)[t];
  const float4 bb = ((const float4*)bta)[t];
  bf16x4 o;
  o[0] = (__bf16)(d0 * rstd * gg.x + bb.x);
  o[1] = (__bf16)(d1 * rstd * gg.y + bb.y);
  o[2] = (__bf16)(d2 * rstd * gg.z + bb.z);
  o[3] = (__bf16)(d3 * rstd * gg.w + bb.w);
  ((bf16x4*)out)[(size_t)row * 256 + t] = o;
}

// ---------------- GEMM: C[8192][N] = A[8192][K](bf16) * Bt[N][K](bf16) + bias
// 128x128 tile, BK=64, XOR-swizzled LDS (0 conflicts), 4 waves (2x2 of 64x64),
// inner: 32x32x16 MFMA (2x2 per wave, 4 k-steps).
template <int EPI, int N, int K>
__global__ __launch_bounds__(256, 2) void gemm_bt(const __bf16* __restrict__ A,
                                                  const __bf16* __restrict__ Bt,
                                                  const float* __restrict__ bias,
                                                  const float* __restrict__ res,
                                                  void* __restrict__ out,
                                                  void* __restrict__ out2) {
  __shared__ __bf16 lA[128 * 64];
  __shared__ __bf16 lB[128 * 64];
  const int t = threadIdx.x;
  const int wave = t >> 6, lane = t & 63;
  const int l32 = lane & 31, hi = lane >> 5;

  // XCD-aware tile mapping (Mtiles = 64, divisible by 8)
  constexpr int Ntiles = N / 128;
  const int flat = blockIdx.y * Ntiles + blockIdx.x;
  const int xcd = flat & 7;
  const int local = flat >> 3;
  const int tn = local % Ntiles;
  const int tm = (local / Ntiles) * 8 + xcd;
  const int m0 = tm * 128, n0 = tn * 128;
  const int wm = (wave & 1) * 64, wn = (wave >> 1) * 64;

  f32x16 acc[2][2] = {};

  // staging: thread t covers rows {srow, srow+32, srow+64, srow+96}; 16B chunk
  // slot (t%8) holds global chunk (t%8)^(srow&7)  (XOR swizzle on the SOURCE,
  // LDS dest stays lane-contiguous as global_load_lds requires).
  const int srow = t >> 3;
  const int schunk = (t & 7) ^ (srow & 7);
  const unsigned aOff = (unsigned)(m0 + srow) * K + schunk * 8;
  const unsigned bOff = (unsigned)(n0 + srow) * K + schunk * 8;

  // LDS read: frag for m-tile mi, k-step kk is row (wm+mi*32+l32), chunk
  // (kk*2+hi) XOR-swizzled by row&7 = l32&7.
  const int swz = l32 & 7;
  const int aBase = (wm + l32) * 64;
  const int bBase = (wn + l32) * 64;

  for (int k0 = 0; k0 < K; k0 += 64) {
#pragma unroll
    for (int i = 0; i < 4; i++) {
      async_copy16((A + k0 + i * 32 * K) + aOff, lA + i * 2048 + t * 8);
      async_copy16((Bt + k0 + i * 32 * K) + bOff, lB + i * 2048 + t * 8);
    }
    __syncthreads();
#pragma unroll
    for (int kk = 0; kk < 4; kk++) {
      const int sl = ((kk * 2 + hi) ^ swz) * 8;
      bf16x8 af[2], bf[2];
#pragma unroll
      for (int i = 0; i < 2; i++) {
        af[i] = *(const bf16x8*)&lA[aBase + i * 2048 + sl];
        bf[i] = *(const bf16x8*)&lB[bBase + i * 2048 + sl];
      }
#pragma unroll
      for (int mi = 0; mi < 2; mi++)
#pragma unroll
        for (int ni = 0; ni < 2; ni++)
          acc[mi][ni] = __builtin_amdgcn_mfma_f32_32x32x16_bf16(af[mi], bf[ni], acc[mi][ni], 0, 0, 0);
    }
    __syncthreads();
  }

  // epilogue. 32x32 C/D layout: col = lane&31, row = (reg&3)+8*(reg>>2)+4*(lane>>5)
#pragma unroll
  for (int mi = 0; mi < 2; mi++) {
    const int r0 = m0 + wm + mi * 32 + 4 * hi;
#pragma unroll
    for (int ni = 0; ni < 2; ni++) {
      const int gc = n0 + wn + ni * 32 + l32;
      const float bv = bias[gc];
#pragma unroll
      for (int reg = 0; reg < 16; reg++) {
        float v = acc[mi][ni][reg] + bv;
        const int row = r0 + (reg & 3) + 8 * (reg >> 2);
        if (EPI == EPI_GELU) {
          v = 0.5f * v * (1.0f + erff(v * 0.70710678118654752f));
          ((__bf16*)out)[(size_t)row * N + gc] = (__bf16)v;
        } else if (EPI == EPI_RES) {
          ((float*)out)[(size_t)row * N + gc] = v + res[(size_t)row * N + gc];
        } else { // EPI_QKV: Q|K -> qk[8192][2048]; V -> Vt[b][h][d][s]
          if (gc < 2048) {
            ((__bf16*)out)[(size_t)row * 2048 + gc] = (__bf16)v;
          } else {
            const int d = gc & 63, hh = (gc - 2048) >> 6;
            const int bb = row >> 9, ss = row & 511;
            ((__bf16*)out2)[(((size_t)bb * 16 + hh) * 64 + d) * 512 + ss] = (__bf16)v;
          }
        }
      }
    }
  }
}

// ---------------- flash attention: block = (b, h, 64 q-rows), 4 waves x 16 q-rows
// flat grid 2048, swizzled so the 8 q-tiles of one (b,h) share an XCD (K/V L2 reuse)
__global__ __launch_bounds__(256) void attn_kernel(const __bf16* __restrict__ qk,
                                                   const __bf16* __restrict__ Vt,
                                                   __bf16* __restrict__ outA) {
  __shared__ __bf16 lK[64 * 64];      // [key][d]
  __shared__ __bf16 lV[64 * 64];      // [d][key]  (pre-transposed source)
  __shared__ __bf16 lP[4][16 * 64];   // per-wave P relayout buffer
  const int t = threadIdx.x, wave = t >> 6, lane = t & 63;
  const int lm = lane & 15, lq = lane >> 4;
  const int flat = blockIdx.x;
  const int xcd = flat & 7, local = flat >> 3;
  const int qt = local & 7;
  const int bh = (local >> 3) * 8 + xcd;
  const int h = bh & 15, b = bh >> 4;
  const int q0 = qt * 64 + wave * 16;

  // Q A-operand frags: A[m=lane&15][k=quad*8+j], two 32-wide d chunks
  const size_t qrow = (size_t)(b * 512 + q0 + lm) * 2048 + h * 64;
  bf16x8 aq0 = *(const bf16x8*)&qk[qrow + lq * 8];
  bf16x8 aq1 = *(const bf16x8*)&qk[qrow + 32 + lq * 8];

  float mrow[4] = {-3e38f, -3e38f, -3e38f, -3e38f};
  float lrow[4] = {0.f, 0.f, 0.f, 0.f};
  f32x4 o[4] = {};

  const __bf16* kSrc = qk + (size_t)(b * 512 + (t >> 3)) * 2048 + 1024 + h * 64 + (t & 7) * 8;
  const __bf16* vSrc = Vt + ((size_t)bh * 64 + (t >> 3)) * 512 + (t & 7) * 8;

  for (int kt = 0; kt < 8; kt++) {
    async_copy16(kSrc + (size_t)(kt * 64) * 2048, lK + t * 8);
    async_copy16(kSrc + (size_t)(kt * 64 + 32) * 2048, lK + 2048 + t * 8);
    async_copy16(vSrc + kt * 64, lV + t * 8);
    async_copy16(vSrc + kt * 64 + (size_t)32 * 512, lV + 2048 + t * 8);
    __syncthreads();

    // S = Q Kt^T  (16 q x 64 keys per wave)
    f32x4 s[4];
#pragma unroll
    for (int ni = 0; ni < 4; ni++) {
      bf16x8 bk0 = *(const bf16x8*)&lK[(ni * 16 + lm) * 64 + lq * 8];
      bf16x8 bk1 = *(const bf16x8*)&lK[(ni * 16 + lm) * 64 + 32 + lq * 8];
      f32x4 z = {};
      z = __builtin_amdgcn_mfma_f32_16x16x32_bf16(aq0, bk0, z, 0, 0, 0);
      z = __builtin_amdgcn_mfma_f32_16x16x32_bf16(aq1, bk1, z, 0, 0, 0);
      s[ni] = z;
    }
#pragma unroll
    for (int ni = 0; ni < 4; ni++)
#pragma unroll
      for (int r = 0; r < 4; r++) s[ni][r] *= 0.125f; // 1/sqrt(64)

    // online softmax; 16 lanes (one quad-row group) share each row
    float mnew[4], alpha[4];
#pragma unroll
    for (int r = 0; r < 4; r++) {
      float mx = fmaxf(fmaxf(s[0][r], s[1][r]), fmaxf(s[2][r], s[3][r]));
#pragma unroll
      for (int off = 1; off < 16; off <<= 1) mx = fmaxf(mx, __shfl_xor(mx, off));
      mnew[r] = fmaxf(mrow[r], mx);
      alpha[r] = __expf(mrow[r] - mnew[r]);
      mrow[r] = mnew[r];
    }
    float rs[4] = {0.f, 0.f, 0.f, 0.f};
#pragma unroll
    for (int ni = 0; ni < 4; ni++)
#pragma unroll
      for (int r = 0; r < 4; r++) {
        const float p = __expf(s[ni][r] - mnew[r]);
        s[ni][r] = p;
        rs[r] += p;
      }
#pragma unroll
    for (int r = 0; r < 4; r++) {
#pragma unroll
      for (int off = 1; off < 16; off <<= 1) rs[r] += __shfl_xor(rs[r], off);
      lrow[r] = lrow[r] * alpha[r] + rs[r];
    }

    // P: C-layout -> A-operand layout via per-wave LDS round trip (m120)
#pragma unroll
    for (int ni = 0; ni < 4; ni++)
#pragma unroll
      for (int r = 0; r < 4; r++)
        lP[wave][(lq * 4 + r) * 64 + ni * 16 + lm] = (__bf16)s[ni][r];
    asm volatile("s_waitcnt lgkmcnt(0)" ::: "memory");
    bf16x8 ap0 = *(const bf16x8*)&lP[wave][lm * 64 + lq * 8];
    bf16x8 ap1 = *(const bf16x8*)&lP[wave][lm * 64 + 32 + lq * 8];

#pragma unroll
    for (int di = 0; di < 4; di++)
#pragma unroll
      for (int r = 0; r < 4; r++) o[di][r] *= alpha[r];

    // O += P Vtile ; B-operand n = d (from lV[d][key], contiguous along key)
#pragma unroll
    for (int di = 0; di < 4; di++) {
      bf16x8 bv0 = *(const bf16x8*)&lV[(di * 16 + lm) * 64 + lq * 8];
      bf16x8 bv1 = *(const bf16x8*)&lV[(di * 16 + lm) * 64 + 32 + lq * 8];
      o[di] = __builtin_amdgcn_mfma_f32_16x16x32_bf16(ap0, bv0, o[di], 0, 0, 0);
      o[di] = __builtin_amdgcn_mfma_f32_16x16x32_bf16(ap1, bv1, o[di], 0, 0, 0);
    }
    __syncthreads();
  }

#pragma unroll
  for (int di = 0; di < 4; di++)
#pragma unroll
    for (int r = 0; r < 4; r++) {
      const float v = o[di][r] / lrow[r];
      outA[(size_t)(b * 512 + q0 + lq * 4 + r) * 1024 + h * 64 + di * 16 + lm] = (__bf16)v;
    }
}

extern "C" void kernel_launch(void* const* d_in, const int* in_sizes, int n_in,
                              void* d_out, int out_size, void* d_ws, size_t ws_size,
                              hipStream_t stream) {
  const float* input = (const float*)d_in[0];
  const float* ln1_g = (const float*)d_in[1];
  const float* ln1_b = (const float*)d_in[2];
  const float* wq = (const float*)d_in[3];
  const float* bq = (const float*)d_in[4];
  const float* wk = (const float*)d_in[5];
  const float* bk = (const float*)d_in[6];
  const float* wv = (const float*)d_in[7];
  const float* bv = (const float*)d_in[8];
  const float* wo = (const float*)d_in[9];
  const float* bo = (const float*)d_in[10];
  const float* ln2_g = (const float*)d_in[11];
  const float* ln2_b = (const float*)d_in[12];
  const float* w1 = (const float*)d_in[13];
  const float* b1 = (const float*)d_in[14];
  const float* w2 = (const float*)d_in[15];
  const float* b2 = (const float*)d_in[16];

  char* ws = (char*)d_ws;
  __bf16* wqkvT = (__bf16*)(ws + 0);
  __bf16* woT   = (__bf16*)(ws + ((size_t)6 << 20));
  __bf16* w1T   = (__bf16*)(ws + ((size_t)8 << 20));
  __bf16* w2T   = (__bf16*)(ws + ((size_t)16 << 20));
  __bf16* qkbuf = (__bf16*)(ws + ((size_t)24 << 20));
  __bf16* vtbuf = (__bf16*)(ws + ((size_t)56 << 20));
  __bf16* abuf  = (__bf16*)(ws + ((size_t)72 << 20));
  float*  xbuf  = (float*) (ws + ((size_t)24 << 20));
  __bf16* ylnbuf= (__bf16*)(ws + ((size_t)56 << 20));
  __bf16* hbuf  = (__bf16*)(ws + ((size_t)72 << 20));
  float*  bqkv  = (float*) (ws + ((size_t)136 << 20));

  const dim3 blk(256);
  prep_weights<<<12300, blk, 0, stream>>>(wq, wk, wv, wo, w1, w2, bq, bk, bv,
                                          wqkvT, woT, w1T, w2T, bqkv);

  ln_kernel<<<8192, blk, 0, stream>>>(input, ln1_g, ln1_b, abuf);
  gemm_bt<EPI_QKV, 3072, 1024><<<dim3(24, 64), blk, 0, stream>>>(
      abuf, wqkvT, bqkv, nullptr, qkbuf, vtbuf);
  attn_kernel<<<2048, blk, 0, stream>>>(qkbuf, vtbuf, abuf);
  gemm_bt<EPI_RES, 1024, 1024><<<dim3(8, 64), blk, 0, stream>>>(
      abuf, woT, bo, input, xbuf, nullptr);
  ln_kernel<<<8192, blk, 0, stream>>>(xbuf, ln2_g, ln2_b, ylnbuf);
  gemm_bt<EPI_GELU, 4096, 1024><<<dim3(32, 64), blk, 0, stream>>>(
      ylnbuf, w1T, b1, nullptr, hbuf, nullptr);
  gemm_bt<EPI_RES, 1024, 4096><<<dim3(8, 64), blk, 0, stream>>>(
      hbuf, w2T, b2, xbuf, d_out, nullptr);
}

// Round 5
// 471.981 us; speedup vs baseline: 1.1040x; 1.0794x over previous
//
#include <hip/hip_runtime.h>
#include <hip/hip_bf16.h>

// EncoderBlock: LN1 -> MHA -> +res -> LN2 -> MLP(GELU exact) -> +res
// B=16 S=512 E=1024 F=4096 H=16 D=64, fp32 in/out, bf16 MFMA internally.
//
// R5: revert gemm to R2-exact (16x16x32 + XOR swizzle = measured 0 conflicts,
//     (256,2) occupancy; R4's 32x32 reintroduced 4-way conflicts + worse
//     epilogue coalescing). Attention: key-tile 128 (halve softmax/barrier
//     overhead) + XOR bank swizzle on lK/lV/lP (attn reads were 16-way
//     conflicted, same mechanism the gemm swizzle fixed).
//
// ws layout (bytes):
//   0        wqkvT  [3072][1024] bf16   6 MB   (wq^T|wk^T|wv^T)
//   6 MB     woT    [1024][1024] bf16   2 MB
//   8 MB     w1T    [4096][1024] bf16   8 MB
//   16 MB    w2T    [1024][4096] bf16   8 MB
//   24 MB    qk     [8192][2048] bf16  32 MB   (Q|K)   -> later x fp32 [8192][1024] 32 MB
//   56 MB    Vt     [256][64][512] bf16 16 MB          -> later y_ln bf16 16 MB
//   72 MB    abuf   [8192][1024] bf16  16 MB (ln1/attn)-> later h bf16 [8192][4096] 64 MB (72..136)
//   136 MB   bqkv   [3072] f32  12 KB

typedef __bf16 bf16x8 __attribute__((ext_vector_type(8)));
typedef __bf16 bf16x4 __attribute__((ext_vector_type(4)));
typedef float  f32x4  __attribute__((ext_vector_type(4)));

#define EPI_QKV  0
#define EPI_RES  1
#define EPI_GELU 2

__device__ __forceinline__ void async_copy16(const void* g, void* l) {
  __builtin_amdgcn_global_load_lds((const __attribute__((address_space(1))) void*)g,
                                   (__attribute__((address_space(3))) void*)l, 16, 0, 0);
}

// ---------------- fused weight prep: 6 transposes (fp32->bf16, [K][N]->[N][K]) + bias concat
__global__ __launch_bounds__(256) void prep_weights(
    const float* __restrict__ wq, const float* __restrict__ wk,
    const float* __restrict__ wv, const float* __restrict__ wo,
    const float* __restrict__ w1, const float* __restrict__ w2,
    const float* __restrict__ bq, const float* __restrict__ bk,
    const float* __restrict__ bv,
    __bf16* __restrict__ wqkvT, __bf16* __restrict__ woT,
    __bf16* __restrict__ w1T, __bf16* __restrict__ w2T, float* __restrict__ bqkv) {
  const int bid = blockIdx.x;
  if (bid >= 12288) { // 12 bias blocks -> 3072 elements
    const int i = (bid - 12288) * 256 + threadIdx.x;
    bqkv[i] = (i < 1024) ? bq[i] : ((i < 2048) ? bk[i - 1024] : bv[i - 2048]);
    return;
  }
  const float* in;
  __bf16* out;
  int K, N, tile;
  if (bid < 4096) { // four 1024x1024 weights, 1024 tiles (32x32) each
    const int w = bid >> 10;
    tile = bid & 1023;
    in = (w == 0) ? wq : (w == 1) ? wk : (w == 2) ? wv : wo;
    out = (w == 3) ? woT : (wqkvT + (size_t)w * 1024 * 1024);
    K = 1024; N = 1024;
  } else if (bid < 8192) { tile = bid - 4096; in = w1; out = w1T; K = 1024; N = 4096; }
  else                   { tile = bid - 8192; in = w2; out = w2T; K = 4096; N = 1024; }
  const int ntx = N >> 5;
  const int bx = tile % ntx, by = tile / ntx;
  const int n0 = bx * 32, k0 = by * 32;

  __shared__ float tilebuf[32][33];
  const int tx = threadIdx.x & 31, ty = threadIdx.x >> 5; // 32x8
#pragma unroll
  for (int i = 0; i < 4; i++)
    tilebuf[ty + i * 8][tx] = in[(size_t)(k0 + ty + i * 8) * N + n0 + tx];
  __syncthreads();
#pragma unroll
  for (int i = 0; i < 4; i++)
    out[(size_t)(n0 + ty + i * 8) * K + k0 + tx] = (__bf16)tilebuf[tx][ty + i * 8];
}

// ---------------- layernorm: one block per row (E=1024, 256 thr * float4)
__device__ __forceinline__ float block_sum(float v, float* red) {
#pragma unroll
  for (int off = 32; off; off >>= 1) v += __shfl_down(v, off);
  const int w = threadIdx.x >> 6;
  __syncthreads();
  if ((threadIdx.x & 63) == 0) red[w] = v;
  __syncthreads();
  return red[0] + red[1] + red[2] + red[3];
}

__global__ __launch_bounds__(256) void ln_kernel(const float* __restrict__ x,
                                                 const float* __restrict__ g,
                                                 const float* __restrict__ bta,
                                                 __bf16* __restrict__ out) {
  __shared__ float red[8];
  const int row = blockIdx.x, t = threadIdx.x;
  const float4 v = ((const float4*)(x + (size_t)row * 1024))[t];
  float s = v.x + v.y + v.z + v.w;
  s = block_sum(s, red);
  const float mean = s * (1.0f / 1024.0f);
  const float d0 = v.x - mean, d1 = v.y - mean, d2 = v.z - mean, d3 = v.w - mean;
  float vs = d0 * d0 + d1 * d1 + d2 * d2 + d3 * d3;
  vs = block_sum(vs, red);
  const float rstd = rsqrtf(vs * (1.0f / 1024.0f) + 1e-5f);
  const float4 gg = ((const float4*)g)[t];
  const float4 bb = ((const float4*)bta)[t];
  bf16x4 o;
  o[0] = (__bf16)(d0 * rstd * gg.x + bb.x);
  o[1] = (__bf16)(d1 * rstd * gg.y + bb.y);
  o[2] = (__bf16)(d2 * rstd * gg.z + bb.z);
  o[3] = (__bf16)(d3 * rstd * gg.w + bb.w);
  ((bf16x4*)out)[(size_t)row * 256 + t] = o;
}

// ---------------- GEMM: C[8192][N] = A[8192][K](bf16) * Bt[N][K](bf16) + bias
// R2-exact: 128x128 tile, BK=64, XOR-swizzled LDS (0 conflicts), 4 waves,
// 16x16x32 MFMA, launch_bounds(256,2).
template <int EPI>
__global__ __launch_bounds__(256, 2) void gemm_bt(const __bf16* __restrict__ A,
                                                  const __bf16* __restrict__ Bt,
                                                  const float* __restrict__ bias,
                                                  const float* __restrict__ res,
                                                  void* __restrict__ out,
                                                  void* __restrict__ out2,
                                                  int N, int K) {
  __shared__ __bf16 lA[128 * 64];
  __shared__ __bf16 lB[128 * 64];
  const int t = threadIdx.x;
  const int wave = t >> 6, lane = t & 63;
  const int lm = lane & 15, lq = lane >> 4;

  // XCD-aware tile mapping (Mtiles = 64, divisible by 8)
  const int Ntiles = gridDim.x;
  const int flat = blockIdx.y * Ntiles + blockIdx.x;
  const int xcd = flat & 7;
  const int local = flat >> 3;
  const int tn = local % Ntiles;
  const int tm = (local / Ntiles) * 8 + xcd;
  const int m0 = tm * 128, n0 = tn * 128;
  const int wm = (wave & 1) * 64, wn = (wave >> 1) * 64;

  f32x4 acc[4][4] = {};

  // staging: thread t covers rows {srow+32i}; LDS slot (t%8) holds global
  // chunk (t%8)^(srow&7)  (XOR swizzle on the SOURCE; async dest stays
  // lane-contiguous as global_load_lds requires).
  const int srow = t >> 3, sslot = t & 7;
  const int schunk = sslot ^ (srow & 7);
  const __bf16* aSrc = A + (size_t)(m0 + srow) * K + schunk * 8;
  const __bf16* bSrc = Bt + (size_t)(n0 + srow) * K + schunk * 8;

  for (int k0 = 0; k0 < K; k0 += 64) {
#pragma unroll
    for (int i = 0; i < 4; i++) {
      async_copy16(aSrc + (size_t)(i * 32) * K, lA + i * 2048 + t * 8);
      async_copy16(bSrc + (size_t)(i * 32) * K, lB + i * 2048 + t * 8);
    }
    aSrc += 64; bSrc += 64;
    __syncthreads();
#pragma unroll
    for (int kk = 0; kk < 2; kk++) {
      bf16x8 af[4], bf[4];
      const int slot = (kk * 4 + lq) ^ (lm & 7); // frag row&7 == lm&7
#pragma unroll
      for (int i = 0; i < 4; i++) {
        af[i] = *(const bf16x8*)&lA[(wm + i * 16 + lm) * 64 + slot * 8];
        bf[i] = *(const bf16x8*)&lB[(wn + i * 16 + lm) * 64 + slot * 8];
      }
#pragma unroll
      for (int mi = 0; mi < 4; mi++)
#pragma unroll
        for (int ni = 0; ni < 4; ni++)
          acc[mi][ni] = __builtin_amdgcn_mfma_f32_16x16x32_bf16(af[mi], bf[ni], acc[mi][ni], 0, 0, 0);
    }
    __syncthreads();
  }

  // epilogue. C/D layout: col = lane&15, row = (lane>>4)*4 + reg  [m89/m91]
#pragma unroll
  for (int mi = 0; mi < 4; mi++) {
    const int gr = m0 + wm + mi * 16 + lq * 4;
#pragma unroll
    for (int ni = 0; ni < 4; ni++) {
      const int gc = n0 + wn + ni * 16 + lm;
      const float bv = bias[gc];
#pragma unroll
      for (int r = 0; r < 4; r++) {
        float v = acc[mi][ni][r] + bv;
        const int row = gr + r;
        if (EPI == EPI_GELU) {
          v = 0.5f * v * (1.0f + erff(v * 0.70710678118654752f));
          ((__bf16*)out)[(size_t)row * N + gc] = (__bf16)v;
        } else if (EPI == EPI_RES) {
          ((float*)out)[(size_t)row * N + gc] = v + res[(size_t)row * N + gc];
        } else { // EPI_QKV: Q|K -> qk[8192][2048]; V -> Vt[b][h][d][s]
          if (gc < 2048) {
            ((__bf16*)out)[(size_t)row * 2048 + gc] = (__bf16)v;
          } else {
            const int d = gc & 63, hh = (gc - 2048) >> 6;
            const int bb = row >> 9, ss = row & 511;
            ((__bf16*)out2)[(((size_t)bb * 16 + hh) * 64 + d) * 512 + ss] = (__bf16)v;
          }
        }
      }
    }
  }
}

// ---------------- flash attention: block = (b, h, 64 q-rows), 4 waves x 16 q-rows
// key-tile 128 (4 iters), XOR-swizzled lK/lV/lP (conflict-free reads).
// flat grid 2048, swizzled so the 8 q-tiles of one (b,h) share an XCD.
__global__ __launch_bounds__(256) void attn_kernel(const __bf16* __restrict__ qk,
                                                   const __bf16* __restrict__ Vt,
                                                   __bf16* __restrict__ outA) {
  __shared__ __bf16 lK[128 * 64];     // [key][d], 16B chunks XOR'd by key&7
  __shared__ __bf16 lV[64 * 128];     // [d][key], 16B chunks XOR'd by d&7
  __shared__ __bf16 lP[4][16 * 128];  // per-wave P, chunks XOR'd by q&7
  const int t = threadIdx.x, wave = t >> 6, lane = t & 63;
  const int lm = lane & 15, lq = lane >> 4;
  const int sw = lm & 7;
  const int flat = blockIdx.x;
  const int xcd = flat & 7, local = flat >> 3;
  const int qt = local & 7;
  const int bh = (local >> 3) * 8 + xcd;
  const int h = bh & 15, b = bh >> 4;
  const int q0 = qt * 64 + wave * 16;

  // Q A-operand frags: A[m=lane&15][k=quad*8+j], two 32-wide d chunks
  const size_t qrow = (size_t)(b * 512 + q0 + lm) * 2048 + h * 64;
  bf16x8 aq0 = *(const bf16x8*)&qk[qrow + lq * 8];
  bf16x8 aq1 = *(const bf16x8*)&qk[qrow + 32 + lq * 8];

  float mrow[4] = {-3e38f, -3e38f, -3e38f, -3e38f};
  float lrow[4] = {0.f, 0.f, 0.f, 0.f};
  f32x4 o[4] = {};

  // K staging: row = t>>3 (+32/round), chunk slot t&7 holds global chunk (t&7)^(row&7)
  const int krow = t >> 3;
  const int kchunk = (t & 7) ^ (krow & 7);
  const __bf16* kSrc = qk + (size_t)(b * 512 + krow) * 2048 + 1024 + h * 64 + kchunk * 8;
  // V staging: d-row = t>>4 (+16/round), slot t&15 holds global key-chunk (t&15)^(d&7)
  const int vrow = t >> 4;
  const int vchunk = (t & 15) ^ (vrow & 7);
  const __bf16* vSrc = Vt + ((size_t)bh * 64 + vrow) * 512 + vchunk * 8;

  for (int kt = 0; kt < 4; kt++) {
#pragma unroll
    for (int i = 0; i < 4; i++) {
      async_copy16(kSrc + (size_t)(kt * 128 + i * 32) * 2048, lK + i * 2048 + t * 8);
      async_copy16(vSrc + kt * 128 + (size_t)(i * 16) * 512, lV + i * 2048 + t * 8);
    }
    __syncthreads();

    // S = Q K^T  (16 q x 128 keys per wave)
    f32x4 s[8];
#pragma unroll
    for (int ni = 0; ni < 8; ni++) {
      bf16x8 bk0 = *(const bf16x8*)&lK[(ni * 16 + lm) * 64 + ((lq ^ sw) * 8)];
      bf16x8 bk1 = *(const bf16x8*)&lK[(ni * 16 + lm) * 64 + (((4 + lq) ^ sw) * 8)];
      f32x4 z = {};
      z = __builtin_amdgcn_mfma_f32_16x16x32_bf16(aq0, bk0, z, 0, 0, 0);
      z = __builtin_amdgcn_mfma_f32_16x16x32_bf16(aq1, bk1, z, 0, 0, 0);
      s[ni] = z;
    }
#pragma unroll
    for (int ni = 0; ni < 8; ni++)
#pragma unroll
      for (int r = 0; r < 4; r++) s[ni][r] *= 0.125f; // 1/sqrt(64)

    // online softmax; 16 lanes (one quad-row group) share each row
    float mnew[4], alpha[4];
#pragma unroll
    for (int r = 0; r < 4; r++) {
      float mx = s[0][r];
#pragma unroll
      for (int ni = 1; ni < 8; ni++) mx = fmaxf(mx, s[ni][r]);
#pragma unroll
      for (int off = 1; off < 16; off <<= 1) mx = fmaxf(mx, __shfl_xor(mx, off));
      mnew[r] = fmaxf(mrow[r], mx);
      alpha[r] = __expf(mrow[r] - mnew[r]);
      mrow[r] = mnew[r];
    }
    float rs[4] = {0.f, 0.f, 0.f, 0.f};
#pragma unroll
    for (int ni = 0; ni < 8; ni++)
#pragma unroll
      for (int r = 0; r < 4; r++) {
        const float p = __expf(s[ni][r] - mnew[r]);
        s[ni][r] = p;
        rs[r] += p;
      }
#pragma unroll
    for (int r = 0; r < 4; r++) {
#pragma unroll
      for (int off = 1; off < 16; off <<= 1) rs[r] += __shfl_xor(rs[r], off);
      lrow[r] = lrow[r] * alpha[r] + rs[r];
    }

    // P: C-layout -> A-operand layout via per-wave LDS round trip, XOR'd by q&7
#pragma unroll
    for (int ni = 0; ni < 8; ni++) {
      const int chunk = ni * 2 + (lm >> 3);
#pragma unroll
      for (int r = 0; r < 4; r++) {
        const int q = lq * 4 + r;
        lP[wave][q * 128 + ((chunk ^ (q & 7)) * 8) + (lm & 7)] = (__bf16)s[ni][r];
      }
    }
    asm volatile("s_waitcnt lgkmcnt(0)" ::: "memory");
    bf16x8 ap[4];
#pragma unroll
    for (int kc = 0; kc < 4; kc++)
      ap[kc] = *(const bf16x8*)&lP[wave][lm * 128 + (((kc * 4 + lq) ^ sw) * 8)];

#pragma unroll
    for (int di = 0; di < 4; di++)
#pragma unroll
      for (int r = 0; r < 4; r++) o[di][r] *= alpha[r];

    // O += P V ; B-operand n = d (lV[d][key], key contiguous, XOR'd by d&7)
#pragma unroll
    for (int di = 0; di < 4; di++) {
#pragma unroll
      for (int kc = 0; kc < 4; kc++) {
        bf16x8 bv = *(const bf16x8*)&lV[(di * 16 + lm) * 128 + (((kc * 4 + lq) ^ sw) * 8)];
        o[di] = __builtin_amdgcn_mfma_f32_16x16x32_bf16(ap[kc], bv, o[di], 0, 0, 0);
      }
    }
    __syncthreads();
  }

#pragma unroll
  for (int di = 0; di < 4; di++)
#pragma unroll
    for (int r = 0; r < 4; r++) {
      const float v = o[di][r] / lrow[r];
      outA[(size_t)(b * 512 + q0 + lq * 4 + r) * 1024 + h * 64 + di * 16 + lm] = (__bf16)v;
    }
}

extern "C" void kernel_launch(void* const* d_in, const int* in_sizes, int n_in,
                              void* d_out, int out_size, void* d_ws, size_t ws_size,
                              hipStream_t stream) {
  const float* input = (const float*)d_in[0];
  const float* ln1_g = (const float*)d_in[1];
  const float* ln1_b = (const float*)d_in[2];
  const float* wq = (const float*)d_in[3];
  const float* bq = (const float*)d_in[4];
  const float* wk = (const float*)d_in[5];
  const float* bk = (const float*)d_in[6];
  const float* wv = (const float*)d_in[7];
  const float* bv = (const float*)d_in[8];
  const float* wo = (const float*)d_in[9];
  const float* bo = (const float*)d_in[10];
  const float* ln2_g = (const float*)d_in[11];
  const float* ln2_b = (const float*)d_in[12];
  const float* w1 = (const float*)d_in[13];
  const float* b1 = (const float*)d_in[14];
  const float* w2 = (const float*)d_in[15];
  const float* b2 = (const float*)d_in[16];

  char* ws = (char*)d_ws;
  __bf16* wqkvT = (__bf16*)(ws + 0);
  __bf16* woT   = (__bf16*)(ws + ((size_t)6 << 20));
  __bf16* w1T   = (__bf16*)(ws + ((size_t)8 << 20));
  __bf16* w2T   = (__bf16*)(ws + ((size_t)16 << 20));
  __bf16* qkbuf = (__bf16*)(ws + ((size_t)24 << 20));
  __bf16* vtbuf = (__bf16*)(ws + ((size_t)56 << 20));
  __bf16* abuf  = (__bf16*)(ws + ((size_t)72 << 20));
  float*  xbuf  = (float*) (ws + ((size_t)24 << 20));
  __bf16* ylnbuf= (__bf16*)(ws + ((size_t)56 << 20));
  __bf16* hbuf  = (__bf16*)(ws + ((size_t)72 << 20));
  float*  bqkv  = (float*) (ws + ((size_t)136 << 20));

  const dim3 blk(256);
  prep_weights<<<12300, blk, 0, stream>>>(wq, wk, wv, wo, w1, w2, bq, bk, bv,
                                          wqkvT, woT, w1T, w2T, bqkv);

  ln_kernel<<<8192, blk, 0, stream>>>(input, ln1_g, ln1_b, abuf);
  gemm_bt<EPI_QKV><<<dim3(24, 64), blk, 0, stream>>>(abuf, wqkvT, bqkv, nullptr,
                                                     qkbuf, vtbuf, 3072, 1024);
  attn_kernel<<<2048, blk, 0, stream>>>(qkbuf, vtbuf, abuf);
  gemm_bt<EPI_RES><<<dim3(8, 64), blk, 0, stream>>>(abuf, woT, bo, input,
                                                    xbuf, nullptr, 1024, 1024);
  ln_kernel<<<8192, blk, 0, stream>>>(xbuf, ln2_g, ln2_b, ylnbuf);
  gemm_bt<EPI_GELU><<<dim3(32, 64), blk, 0, stream>>>(ylnbuf, w1T, b1, nullptr,
                                                      hbuf, nullptr, 4096, 1024);
  gemm_bt<EPI_RES><<<dim3(8, 64), blk, 0, stream>>>(hbuf, w2T, b2, xbuf,
                                                    d_out, nullptr, 1024, 4096);
}